// Round 8
// baseline (64.591 us; speedup 1.0000x reference)
//
#include <hip/hip_runtime.h>

// out[b,e,t] = sum_{s<=t} x[s]*(w0[s]*dv0^(t-s) + w1[t]*dv1^(t-s)) + bias[t]
//   P[t] = dv0*P[t-1] + x[t]*w0[t];  Q[t] = dv1*Q[t-1] + x[t]
//   out[t] = P[t] + w1[t]*Q[t] + bias[t]
// Persistent block at FULL occupancy: 2048 blocks (8/CU), each scans 4 rows
// sequentially. Next row's x prefetched into registers before the current
// row's scan (loads in flight across the raw lgkm-only barrier). ctot double-
// buffered -> one barrier per row. w0 kept resident; w1/bias reloaded per row
// (L1-hot) to keep VGPR <= 64 so __launch_bounds__(256,8) holds 8 blocks/CU.
// Scan: 4-elem segment totals -> wave KS (factor dv^4, A/B independent) ->
// 8 chunk totals via LDS (factor dv^256) -> fixup + fused epilogue.

#define S_LEN 2048
#define THREADS 256
#define RPB 4

typedef float f4 __attribute__((ext_vector_type(4)));

__global__ __launch_bounds__(THREADS, 8)
void crcl_kernel(const float* __restrict__ x,
                 const float* __restrict__ weight,
                 const float* __restrict__ bias,
                 const float* __restrict__ decay,
                 float* __restrict__ out,
                 int nrows)
{
    __shared__ float ctot[2][2][8];     // [buf][p/q][chunk]

    const int t    = (int)threadIdx.x;
    const int lane = t & 63;
    const int w    = t >> 6;
    const long row0 = (long)blockIdx.x * RPB;
    const int sA = t, sB = 256 + t;     // owned f4 segments (unit lane stride)

    // ---- w0 resident; dv-derived constants once per block ----
    const f4* w04 = (const f4*)weight;            // weight[0][:]
    const f4 wA = w04[sA], wB = w04[sB];

    const float dv0 = fminf(fmaxf(decay[0], 0.9f), 1.0f);
    const float dv1 = fminf(fmaxf(decay[1], 0.9f), 1.0f);

    float A4_0 = dv0 * dv0; A4_0 *= A4_0;          // dv0^4
    float A4_1 = dv1 * dv1; A4_1 *= A4_1;          // dv1^4
    float A256_0 = A4_0, A256_1 = A4_1;            // dv^256
#pragma unroll
    for (int b = 0; b < 6; ++b) { A256_0 *= A256_0; A256_1 *= A256_1; }
    const float e4 = (float)(4 * lane);
    const float pw0l = exp2f(e4 * log2f(dv0));     // dv0^(4*lane)
    const float pw1l = exp2f(e4 * log2f(dv1));

    // ---- prologue: row 0 x in flight ----
    long rc = row0; if (rc >= nrows) rc = nrows - 1;
    const f4* xp0 = (const f4*)(x + rc * (long)S_LEN);
    f4 cxA = xp0[sA], cxB = xp0[sB];
    f4 nxA, nxB;

#pragma unroll
    for (int r = 0; r < RPB; ++r) {
        // ---- prefetch next row's x (stays in flight across the barrier) ----
        if (r + 1 < RPB) {
            long rn = row0 + r + 1; if (rn >= nrows) rn = nrows - 1;
            const f4* xp = (const f4*)(x + rn * (long)S_LEN);
            nxA = xp[sA]; nxB = xp[sB];
        }

        // ---- pass 1: per-segment totals ----
        float TAp = 0.0f, TAq = 0.0f, TBp = 0.0f, TBq = 0.0f;
#pragma unroll
        for (int j = 0; j < 4; ++j) {
            TAp = fmaf(dv0, TAp, cxA[j] * wA[j]);
            TAq = fmaf(dv1, TAq, cxA[j]);
            TBp = fmaf(dv0, TBp, cxB[j] * wB[j]);
            TBq = fmaf(dv1, TBq, cxB[j]);
        }

        // ---- wave Kogge-Stone, factor dv^4, A/B independent ----
        float sAp = TAp, sAq = TAq, sBp = TBp, sBq = TBq;
        float k0 = A4_0, k1 = A4_1;
#pragma unroll
        for (int d = 1; d < 64; d <<= 1) {
            const float uAp = __shfl_up(sAp, (unsigned)d, 64);
            const float uAq = __shfl_up(sAq, (unsigned)d, 64);
            const float uBp = __shfl_up(sBp, (unsigned)d, 64);
            const float uBq = __shfl_up(sBq, (unsigned)d, 64);
            if (lane >= d) {
                sAp = fmaf(k0, uAp, sAp);
                sAq = fmaf(k1, uAq, sAq);
                sBp = fmaf(k0, uBp, sBp);
                sBq = fmaf(k1, uBq, sBq);
            }
            k0 *= k0;
            k1 *= k1;
        }
        float eAp = __shfl_up(sAp, 1u, 64);
        float eAq = __shfl_up(sAq, 1u, 64);
        float eBp = __shfl_up(sBp, 1u, 64);
        float eBq = __shfl_up(sBq, 1u, 64);
        if (lane == 0) { eAp = eAq = eBp = eBq = 0.0f; }

        // ---- cross-wave exchange: double-buffered slots, lgkm-only drain ----
        const int rb = r & 1;
        if (lane == 63) {
            ctot[rb][0][w]     = sAp;  ctot[rb][1][w]     = sAq;
            ctot[rb][0][4 + w] = sBp;  ctot[rb][1][4 + w] = sBq;
        }
        asm volatile("s_waitcnt lgkmcnt(0)" ::: "memory");
        __builtin_amdgcn_s_barrier();   // x prefetch stays in flight (vmcnt)

        float GAp = 0.0f, GAq = 0.0f;   // carry into chunk w
#pragma unroll
        for (int d = 0; d < 3; ++d) {
            if (d < w) {
                GAp = fmaf(A256_0, GAp, ctot[rb][0][d]);
                GAq = fmaf(A256_1, GAq, ctot[rb][1][d]);
            }
        }
        float GBp = 0.0f, GBq = 0.0f;   // carry into chunk 4+w
#pragma unroll
        for (int d = 0; d < 7; ++d) {
            if (d < 4 + w) {
                GBp = fmaf(A256_0, GBp, ctot[rb][0][d]);
                GBq = fmaf(A256_1, GBq, ctot[rb][1][d]);
            }
        }
        const float cinAp = fmaf(GAp, pw0l, eAp);
        const float cinAq = fmaf(GAq, pw1l, eAq);
        const float cinBp = fmaf(GBp, pw0l, eBp);
        const float cinBq = fmaf(GBq, pw1l, eBq);

        // ---- pass 2: w1/bias reloaded (L1-hot), fused epilogue ----
        const f4* w14 = (const f4*)(weight + S_LEN);
        const f4* b4  = (const f4*)bias;
        f4 yA, yB;
        {
            const f4 vv = w14[sA];
            const f4 bv = b4[sA];
            float p = cinAp, q = cinAq;
#pragma unroll
            for (int j = 0; j < 4; ++j) {
                p = fmaf(dv0, p, cxA[j] * wA[j]);
                q = fmaf(dv1, q, cxA[j]);
                yA[j] = fmaf(vv[j], q, p) + bv[j];
            }
        }
        {
            const f4 vv = w14[sB];
            const f4 bv = b4[sB];
            float p = cinBp, q = cinBq;
#pragma unroll
            for (int j = 0; j < 4; ++j) {
                p = fmaf(dv0, p, cxB[j] * wB[j]);
                q = fmaf(dv1, q, cxB[j]);
                yB[j] = fmaf(vv[j], q, p) + bv[j];
            }
        }

        long rs = row0 + r; if (rs >= nrows) rs = nrows - 1;
        f4* o4 = (f4*)(out + rs * (long)S_LEN);
        o4[sA] = yA;
        o4[sB] = yB;

        // ---- rotate prefetch buffer (compile-time after unroll) ----
        if (r + 1 < RPB) { cxA = nxA; cxB = nxB; }
    }
}

extern "C" void kernel_launch(void* const* d_in, const int* in_sizes, int n_in,
                              void* d_out, int out_size, void* d_ws, size_t ws_size,
                              hipStream_t stream) {
    const float* x      = (const float*)d_in[0];
    const float* weight = (const float*)d_in[1];
    const float* bias   = (const float*)d_in[2];
    const float* decay  = (const float*)d_in[3];
    float* out = (float*)d_out;

    const int nrows   = in_sizes[0] / S_LEN;      // B*E = 8192
    const int nblocks = (nrows + RPB - 1) / RPB;  // 2048 = 8 blocks/CU x 256 CU
    hipLaunchKernelGGL(crcl_kernel, dim3(nblocks), dim3(THREADS), 0, stream,
                       x, weight, bias, decay, out, nrows);
}

// Round 9
// 61.588 us; speedup vs baseline: 1.0488x; 1.0488x over previous
//
#include <hip/hip_runtime.h>

// out[b,e,t] = sum_{s<=t} x[s]*(w0[s]*dv0^(t-s) + w1[t]*dv1^(t-s)) + bias[t]
//   P[t] = dv0*P[t-1] + x[t]*w0[t];  Q[t] = dv1*Q[t-1] + x[t]
//   out[t] = P[t] + w1[t]*Q[t] + bias[t]
// 4 rows per 256-thread block (2048 blocks = exactly 8 blocks/CU, one
// generation). Row r+1 is prefetched via global_load_lds into an 8 KB LDS
// buffer (double-buffered) while registers compute row r -> 2 rows in
// flight per block at ~56 VGPR (LDS carries the pipeline, not VGPRs).
// Stores are issued AFTER the buffer-swap __syncthreads so no barrier waits
// on a fresh store; the ctot carry exchange uses a raw lgkm-only barrier.
// Scan per row: 4-elem segment totals -> wave KS (factor dv^4, A/B chunks
// independent) -> 8 chunk totals via LDS (factor dv^256) -> fused epilogue.

#define S_LEN 2048
#define THREADS 256
#define RPB 4

typedef float f4 __attribute__((ext_vector_type(4)));
typedef __attribute__((address_space(1))) const void g1void;
typedef __attribute__((address_space(3))) void l3void;

__global__ __launch_bounds__(THREADS, 8)
void crcl_kernel(const float* __restrict__ x,
                 const float* __restrict__ weight,
                 const float* __restrict__ bias,
                 const float* __restrict__ decay,
                 float* __restrict__ out,
                 int nrows)
{
    __shared__ f4 lbuf[2][S_LEN / 4];     // 2 x 8 KiB row buffers
    __shared__ float ctot[2][2][8];       // [row parity][p/q][chunk]

    const int t    = (int)threadIdx.x;
    const int lane = t & 63;
    const int w    = t >> 6;
    const long row0 = (long)blockIdx.x * RPB;
    const int sA = t, sB = 256 + t;       // owned f4 slots (unit lane stride)

    // ---- block-invariant operands, resident for all 4 rows ----
    const f4* w04 = (const f4*)weight;            // weight[0][:]
    const f4* w14 = (const f4*)(weight + S_LEN);  // weight[1][:]
    const f4* b4  = (const f4*)bias;
    const f4 wA = w04[sA], wB = w04[sB];
    const f4 vA = w14[sA], vB = w14[sB];
    const f4 bA = b4[sA],  bB = b4[sB];

    const float dv0 = fminf(fmaxf(decay[0], 0.9f), 1.0f);
    const float dv1 = fminf(fmaxf(decay[1], 0.9f), 1.0f);

    float A4_0 = dv0 * dv0; A4_0 *= A4_0;          // dv0^4
    float A4_1 = dv1 * dv1; A4_1 *= A4_1;          // dv1^4
    float A256_0 = A4_0, A256_1 = A4_1;            // dv^256
#pragma unroll
    for (int b = 0; b < 6; ++b) { A256_0 *= A256_0; A256_1 *= A256_1; }
    const float e4 = (float)(4 * lane);
    const float pw0l = exp2f(e4 * log2f(dv0));     // dv0^(4*lane)
    const float pw1l = exp2f(e4 * log2f(dv1));

    // ---- prologue: stage row 0 into buf 0 ----
    {
        long rr = row0; if (rr >= nrows) rr = nrows - 1;
        const f4* xp = (const f4*)(x + rr * (long)S_LEN);
        __builtin_amdgcn_global_load_lds((g1void*)&xp[sA], (l3void*)&lbuf[0][sA], 16, 0, 0);
        __builtin_amdgcn_global_load_lds((g1void*)&xp[sB], (l3void*)&lbuf[0][sB], 16, 0, 0);
    }
    __syncthreads();
    f4 cxA = lbuf[0][sA], cxB = lbuf[0][sB];

#pragma unroll
    for (int r = 0; r < RPB; ++r) {
        // ---- stage row r+1 into the other buffer (async, in flight
        //      across the whole row-r compute) ----
        if (r + 1 < RPB) {
            long rn = row0 + r + 1; if (rn >= nrows) rn = nrows - 1;
            const f4* xp = (const f4*)(x + rn * (long)S_LEN);
            const int nb = (r + 1) & 1;
            __builtin_amdgcn_global_load_lds((g1void*)&xp[sA], (l3void*)&lbuf[nb][sA], 16, 0, 0);
            __builtin_amdgcn_global_load_lds((g1void*)&xp[sB], (l3void*)&lbuf[nb][sB], 16, 0, 0);
        }

        // ---- pass 1: per-segment totals ----
        float TAp = 0.0f, TAq = 0.0f, TBp = 0.0f, TBq = 0.0f;
#pragma unroll
        for (int j = 0; j < 4; ++j) {
            TAp = fmaf(dv0, TAp, cxA[j] * wA[j]);
            TAq = fmaf(dv1, TAq, cxA[j]);
            TBp = fmaf(dv0, TBp, cxB[j] * wB[j]);
            TBq = fmaf(dv1, TBq, cxB[j]);
        }

        // ---- wave Kogge-Stone, factor dv^4, A/B independent ----
        float sAp = TAp, sAq = TAq, sBp = TBp, sBq = TBq;
        float k0 = A4_0, k1 = A4_1;
#pragma unroll
        for (int d = 1; d < 64; d <<= 1) {
            const float uAp = __shfl_up(sAp, (unsigned)d, 64);
            const float uAq = __shfl_up(sAq, (unsigned)d, 64);
            const float uBp = __shfl_up(sBp, (unsigned)d, 64);
            const float uBq = __shfl_up(sBq, (unsigned)d, 64);
            if (lane >= d) {
                sAp = fmaf(k0, uAp, sAp);
                sAq = fmaf(k1, uAq, sAq);
                sBp = fmaf(k0, uBp, sBp);
                sBq = fmaf(k1, uBq, sBq);
            }
            k0 *= k0;
            k1 *= k1;
        }
        float eAp = __shfl_up(sAp, 1u, 64);
        float eAq = __shfl_up(sAq, 1u, 64);
        float eBp = __shfl_up(sBp, 1u, 64);
        float eBq = __shfl_up(sBq, 1u, 64);
        if (lane == 0) { eAp = eAq = eBp = eBq = 0.0f; }

        // ---- ctot exchange: raw lgkm-only barrier (stores & staging
        //      global-loads stay in flight) ----
        const int rb = r & 1;
        if (lane == 63) {
            ctot[rb][0][w]     = sAp;  ctot[rb][1][w]     = sAq;
            ctot[rb][0][4 + w] = sBp;  ctot[rb][1][4 + w] = sBq;
        }
        asm volatile("s_waitcnt lgkmcnt(0)" ::: "memory");
        __builtin_amdgcn_s_barrier();

        float GAp = 0.0f, GAq = 0.0f;   // carry into chunk w
#pragma unroll
        for (int d = 0; d < 3; ++d) {
            if (d < w) {
                GAp = fmaf(A256_0, GAp, ctot[rb][0][d]);
                GAq = fmaf(A256_1, GAq, ctot[rb][1][d]);
            }
        }
        float GBp = 0.0f, GBq = 0.0f;   // carry into chunk 4+w
#pragma unroll
        for (int d = 0; d < 7; ++d) {
            if (d < 4 + w) {
                GBp = fmaf(A256_0, GBp, ctot[rb][0][d]);
                GBq = fmaf(A256_1, GBq, ctot[rb][1][d]);
            }
        }
        const float cinAp = fmaf(GAp, pw0l, eAp);
        const float cinAq = fmaf(GAq, pw1l, eAq);
        const float cinBp = fmaf(GBp, pw0l, eBp);
        const float cinBq = fmaf(GBq, pw1l, eBq);

        // ---- pass 2: recompute seeded with carry, fused epilogue ----
        f4 yA, yB;
        {
            float p = cinAp, q = cinAq;
#pragma unroll
            for (int j = 0; j < 4; ++j) {
                p = fmaf(dv0, p, cxA[j] * wA[j]);
                q = fmaf(dv1, q, cxA[j]);
                yA[j] = fmaf(vA[j], q, p) + bA[j];
            }
        }
        {
            float p = cinBp, q = cinBq;
#pragma unroll
            for (int j = 0; j < 4; ++j) {
                p = fmaf(dv0, p, cxB[j] * wB[j]);
                q = fmaf(dv1, q, cxB[j]);
                yB[j] = fmaf(vB[j], q, p) + bB[j];
            }
        }

        // ---- buffer swap: __syncthreads drains staging (vmcnt) -- the only
        //      outstanding stores are a full row old (already retired) ----
        if (r + 1 < RPB) {
            __syncthreads();
            const int nb = (r + 1) & 1;
            cxA = lbuf[nb][sA];
            cxB = lbuf[nb][sB];
        }

        // ---- store row r AFTER the swap sync (never waited on fresh) ----
        long rs = row0 + r; if (rs >= nrows) rs = nrows - 1;
        f4* o4 = (f4*)(out + rs * (long)S_LEN);
        o4[sA] = yA;
        o4[sB] = yB;
    }
}

extern "C" void kernel_launch(void* const* d_in, const int* in_sizes, int n_in,
                              void* d_out, int out_size, void* d_ws, size_t ws_size,
                              hipStream_t stream) {
    const float* x      = (const float*)d_in[0];
    const float* weight = (const float*)d_in[1];
    const float* bias   = (const float*)d_in[2];
    const float* decay  = (const float*)d_in[3];
    float* out = (float*)d_out;

    const int nrows   = in_sizes[0] / S_LEN;      // B*E = 8192
    const int nblocks = (nrows + RPB - 1) / RPB;  // 2048 = 8 blocks/CU x 256 CU
    hipLaunchKernelGGL(crcl_kernel, dim3(nblocks), dim3(THREADS), 0, stream,
                       x, weight, bias, decay, out, nrows);
}

// Round 10
// 25.786 us; speedup vs baseline: 2.5049x; 2.3884x over previous
//
#include <hip/hip_runtime.h>

// out[b,e,t] = sum_{s<=t} x[s]*(w0[s]*dv0^(t-s) + w1[t]*dv1^(t-s)) + bias[t]
//   P[t] = dv0*P[t-1] + x[t]*w0[t];  Q[t] = dv1*Q[t-1] + x[t]
//   out[t] = P[t] + w1[t]*Q[t] + bias[t]
// Round-6 structure (best: 26.2us, VGPR 48, no spill) + nontemporal stores.
// One row per 256-thread block. Thread t owns f4 slots t and 256+t (unit
// 16B lane stride on every global access). Scan: 4-elem segment totals ->
// wave Kogge-Stone (factor dv^4, A/B independent) -> 8 chunk totals via
// 64B LDS (factor dv^256, one barrier) -> fixup + fused epilogue -> NT
// float4 stores (write-combine; keep L2/L3 ports clear for the read stream).

#define S_LEN 2048
#define THREADS 256

typedef float f4 __attribute__((ext_vector_type(4)));

__global__ __launch_bounds__(THREADS, 8)
void crcl_kernel(const float* __restrict__ x,
                 const float* __restrict__ weight,
                 const float* __restrict__ bias,
                 const float* __restrict__ decay,
                 float* __restrict__ out)
{
    __shared__ float ctot[2][8];    // [p/q][chunk 0..7], chunk = 64 segments

    const int t    = (int)threadIdx.x;
    const int lane = t & 63;
    const int w    = t >> 6;
    const long row = (long)blockIdx.x;

    // ---- global loads: all unit-lane-stride float4, issued up front ----
    const f4* x4  = (const f4*)(x + row * (long)S_LEN);
    const f4* w04 = (const f4*)weight;            // weight[0][:]
    const f4* w14 = (const f4*)(weight + S_LEN);  // weight[1][:]
    const f4* b4  = (const f4*)bias;

    const int sA = t, sB = 256 + t;               // owned f4 segments
    const f4 xA = x4[sA],  xB = x4[sB];
    const f4 wA = w04[sA], wB = w04[sB];
    const f4 vA = w14[sA], vB = w14[sB];
    const f4 bA = b4[sA],  bB = b4[sB];

    const float dv0 = fminf(fmaxf(decay[0], 0.9f), 1.0f);
    const float dv1 = fminf(fmaxf(decay[1], 0.9f), 1.0f);

    // powers: A4 = dv^4, A256 = dv^256, pwl = dv^(4*lane)
    float A4_0 = dv0 * dv0; A4_0 *= A4_0;
    float A4_1 = dv1 * dv1; A4_1 *= A4_1;
    float A256_0 = A4_0, A256_1 = A4_1;
#pragma unroll
    for (int b = 0; b < 6; ++b) { A256_0 *= A256_0; A256_1 *= A256_1; }
    const float e4 = (float)(4 * lane);
    const float pw0l = exp2f(e4 * log2f(dv0));
    const float pw1l = exp2f(e4 * log2f(dv1));

    // ---- pass 1: per-segment totals (4-fma chains, A/B independent) ----
    float TAp = 0.0f, TAq = 0.0f, TBp = 0.0f, TBq = 0.0f;
#pragma unroll
    for (int j = 0; j < 4; ++j) {
        TAp = fmaf(dv0, TAp, xA[j] * wA[j]);
        TAq = fmaf(dv1, TAq, xA[j]);
        TBp = fmaf(dv0, TBp, xB[j] * wB[j]);
        TBq = fmaf(dv1, TBq, xB[j]);
    }

    // ---- wave Kogge-Stone over lanes, factor A4; A and B independent ----
    float sAp = TAp, sAq = TAq, sBp = TBp, sBq = TBq;
    float k0 = A4_0, k1 = A4_1;
#pragma unroll
    for (int d = 1; d < 64; d <<= 1) {
        const float uAp = __shfl_up(sAp, (unsigned)d, 64);
        const float uAq = __shfl_up(sAq, (unsigned)d, 64);
        const float uBp = __shfl_up(sBp, (unsigned)d, 64);
        const float uBq = __shfl_up(sBq, (unsigned)d, 64);
        if (lane >= d) {
            sAp = fmaf(k0, uAp, sAp);
            sAq = fmaf(k1, uAq, sAq);
            sBp = fmaf(k0, uBp, sBp);
            sBq = fmaf(k1, uBq, sBq);
        }
        k0 *= k0;
        k1 *= k1;
    }
    // exclusive within-chunk prefixes
    float eAp = __shfl_up(sAp, 1u, 64);
    float eAq = __shfl_up(sAq, 1u, 64);
    float eBp = __shfl_up(sBp, 1u, 64);
    float eBq = __shfl_up(sBq, 1u, 64);
    if (lane == 0) { eAp = eAq = eBp = eBq = 0.0f; }

    // ---- chunk totals -> LDS (chunk w from A, chunk 4+w from B) ----
    if (lane == 63) {
        ctot[0][w]     = sAp;  ctot[1][w]     = sAq;
        ctot[0][4 + w] = sBp;  ctot[1][4 + w] = sBq;
    }
    __syncthreads();

    // ---- chunk carry-in: V_c = sum_{d<c} U_d * A256^(c-1-d) ----
    float GAp = 0.0f, GAq = 0.0f;                 // carry into chunk w
#pragma unroll
    for (int d = 0; d < 3; ++d) {
        if (d < w) {
            GAp = fmaf(A256_0, GAp, ctot[0][d]);
            GAq = fmaf(A256_1, GAq, ctot[1][d]);
        }
    }
    float GBp = 0.0f, GBq = 0.0f;                 // carry into chunk 4+w
#pragma unroll
    for (int d = 0; d < 7; ++d) {
        if (d < 4 + w) {
            GBp = fmaf(A256_0, GBp, ctot[0][d]);
            GBq = fmaf(A256_1, GBq, ctot[1][d]);
        }
    }

    // carry into segment = G * dv^(4*lane) + exclusive-wave-prefix
    const float cinAp = fmaf(GAp, pw0l, eAp);
    const float cinAq = fmaf(GAq, pw1l, eAq);
    const float cinBp = fmaf(GBp, pw0l, eBp);
    const float cinBq = fmaf(GBq, pw1l, eBq);

    // ---- pass 2: recompute seeded with carry, fused epilogue ----
    f4 yA, yB;
    {
        float p = cinAp, q = cinAq;
#pragma unroll
        for (int j = 0; j < 4; ++j) {
            p = fmaf(dv0, p, xA[j] * wA[j]);
            q = fmaf(dv1, q, xA[j]);
            yA[j] = fmaf(vA[j], q, p) + bA[j];
        }
    }
    {
        float p = cinBp, q = cinBq;
#pragma unroll
        for (int j = 0; j < 4; ++j) {
            p = fmaf(dv0, p, xB[j] * wB[j]);
            q = fmaf(dv1, q, xB[j]);
            yB[j] = fmaf(vB[j], q, p) + bB[j];
        }
    }

    f4* o4 = (f4*)(out + row * (long)S_LEN);
    __builtin_nontemporal_store(yA, &o4[sA]);   // write-combine, no L2/L3 pollution
    __builtin_nontemporal_store(yB, &o4[sB]);
}

extern "C" void kernel_launch(void* const* d_in, const int* in_sizes, int n_in,
                              void* d_out, int out_size, void* d_ws, size_t ws_size,
                              hipStream_t stream) {
    const float* x      = (const float*)d_in[0];
    const float* weight = (const float*)d_in[1];
    const float* bias   = (const float*)d_in[2];
    const float* decay  = (const float*)d_in[3];
    float* out = (float*)d_out;

    const int nrows = in_sizes[0] / S_LEN;   // B*E = 8192 rows, one block each
    hipLaunchKernelGGL(crcl_kernel, dim3(nrows), dim3(THREADS), 0, stream,
                       x, weight, bias, decay, out);
}